// Round 5
// baseline (212.779 us; speedup 1.0000x reference)
//
#include <hip/hip_runtime.h>
#include <math.h>

#define NQ       8
#define NLAYERS  4
#define OUTC     8
#define BATCH    128
#define LEN      512
#define OUTL     505                 // (512 - 8)/1 + 1
#define NPATCH   (BATCH * OUTL)      // 64640
#define BLK_PER_CH 1010              // 64640 patches / (64 patches per block)

// DPP lane shuffle within quads (full-rate VALU, no LDS).
// quad_perm encodings: xor1 -> [1,0,3,2] = 0xB1 ; xor2 -> [2,3,0,1] = 0x4E
template <int CTRL>
__device__ __forceinline__ float dpp_xor(float x) {
    int i = __float_as_int(x);
    int r = __builtin_amdgcn_update_dpp(0, i, CTRL, 0xF, 0xF, true);
    return __int_as_float(r);
}

// Layout:
//   circuit  = (channel k, patch p); 4 lanes per circuit, 64 amps per lane.
//   lane = (circ_in_wave << 2) | (b0 << 1) | b7
//     b0 = basis bit of wire 0, b7 = basis bit of wire 7 (intra-quad lane bits)
//   reg index r (6 bits): wire q (1..6) -> bit (6-q) of r.
__global__ __launch_bounds__(256) void qconv_kernel(const float* __restrict__ x,
                                                    const float* __restrict__ w,
                                                    float* __restrict__ out) {
    const int lane = threadIdx.x & 63;
    const int wave = threadIdx.x >> 6;
    const int bi   = blockIdx.x;
    const int k    = bi / BLK_PER_CH;           // output channel
    const int pblk = bi % BLK_PER_CH;
    const int patch = pblk * 64 + wave * 16 + (lane >> 2);
    const int b0 = (lane >> 1) & 1;             // wire 0 bit
    const int b7 = lane & 1;                    // wire 7 bit
    const int b  = patch / OUTL;
    const int ol = patch - b * OUTL;
    const float* xp = x + b * LEN + ol;

    // ---- AngleEmbedding: RY(pi*x_q) on |0> -> product state (cos, sin) of half-angle
    float ec[NQ], es[NQ];
#pragma unroll
    for (int q = 0; q < NQ; ++q) {
        float half = xp[q] * 1.5707963267948966f;   // (pi * x)/2
        ec[q] = __cosf(half);
        es[q] = __sinf(half);
    }

    float st[64];
    st[0] = (b0 ? es[0] : ec[0]) * (b7 ? es[7] : ec[7]);
    // expand product over wires 1..6 (reg bits 5..0)
#pragma unroll
    for (int q = 1; q <= 6; ++q) {
        const int m = 1 << (6 - q);
#pragma unroll
        for (int j = (1 << (q - 1)) - 1; j >= 0; --j) {
            float v = st[j * 2 * m];
            st[j * 2 * m + m] = v * es[q];
            st[j * 2 * m]     = v * ec[q];
        }
    }

    const float* wk = w + k * (NLAYERS * NQ);

#pragma unroll 1
    for (int layer = 0; layer < NLAYERS; ++layer) {
        // per-layer weight angles (uniform across lanes)
        float wc[NQ], wsn[NQ];
#pragma unroll
        for (int q = 0; q < NQ; ++q) {
            float half = 0.5f * wk[layer * NQ + q];
            wc[q]  = __cosf(half);
            wsn[q] = __sinf(half);
        }

        // RY wire0 (lane bit1): partner = lane ^ 2
        {
            const float sg = b0 ? wsn[0] : -wsn[0];
#pragma unroll
            for (int r = 0; r < 64; ++r) {
                float p = dpp_xor<0x4E>(st[r]);
                st[r] = fmaf(wc[0], st[r], sg * p);
            }
        }
        // RY wires 1..6 (reg bits 5..0): in-register 2x2 rotations
#pragma unroll
        for (int q = 1; q <= 6; ++q) {
            const int m = 1 << (6 - q);
#pragma unroll
            for (int r = 0; r < 64; ++r) {
                if (r & m) continue;
                float a0 = st[r], a1 = st[r + m];
                st[r]     = fmaf(wc[q], a0, -wsn[q] * a1);
                st[r + m] = fmaf(wc[q], a1,  wsn[q] * a0);
            }
        }
        // RY wire7 (lane bit0): partner = lane ^ 1
        {
            const float sg = b7 ? wsn[7] : -wsn[7];
#pragma unroll
            for (int r = 0; r < 64; ++r) {
                float p = dpp_xor<0xB1>(st[r]);
                st[r] = fmaf(wc[7], st[r], sg * p);
            }
        }

        // CNOT(0,1): ctrl = lane bit b0, tgt = reg bit5 -> conditional reg swap
#pragma unroll
        for (int r = 0; r < 32; ++r) {
            float t0 = st[r], t1 = st[r + 32];
            st[r]      = b0 ? t1 : t0;
            st[r + 32] = b0 ? t0 : t1;
        }
        // CNOT(q,q+1), q=1..5: both bits in regs -> compile-time permutation (free)
#pragma unroll
        for (int q = 1; q <= 5; ++q) {
            const int cm = 1 << (6 - q);
            const int tm = 1 << (5 - q);
#pragma unroll
            for (int r = 0; r < 64; ++r) {
                if ((r & cm) && !(r & tm)) {
                    float t = st[r];
                    st[r] = st[r + tm];
                    st[r + tm] = t;
                }
            }
        }
        // CNOT(6,7): ctrl = reg bit0, tgt = lane bit b7 -> swap odd regs across lane^1
#pragma unroll
        for (int r = 1; r < 64; r += 2) {
            st[r] = dpp_xor<0xB1>(st[r]);
        }
    }

    // ---- <Z^{x8}> = sum amp^2 * (-1)^popcount(index)
    float accp = 0.0f, accm = 0.0f;
#pragma unroll
    for (int r = 0; r < 64; ++r) {
        if (__builtin_popcount(r) & 1) accm = fmaf(st[r], st[r], accm);
        else                           accp = fmaf(st[r], st[r], accp);
    }
    float v = accp - accm;
    if (b0 ^ b7) v = -v;
    // sum across the 4 lanes of this circuit (within quad)
    v += dpp_xor<0xB1>(v);
    v += dpp_xor<0x4E>(v);

    if ((lane & 3) == 0) {
        out[b * (OUTC * OUTL) + k * OUTL + ol] = v;
    }
}

extern "C" void kernel_launch(void* const* d_in, const int* in_sizes, int n_in,
                              void* d_out, int out_size, void* d_ws, size_t ws_size,
                              hipStream_t stream) {
    const float* x = (const float*)d_in[0];     // (128, 1, 512) f32
    const float* w = (const float*)d_in[1];     // (8, 32) f32
    float* out = (float*)d_out;                 // (128, 8, 505) f32
    dim3 grid(OUTC * BLK_PER_CH);               // 8080 blocks
    qconv_kernel<<<grid, 256, 0, stream>>>(x, w, out);
}

// Round 7
// 146.471 us; speedup vs baseline: 1.4527x; 1.4527x over previous
//
#include <hip/hip_runtime.h>
#include <math.h>

#define NQ       8
#define NLAYERS  4
#define OUTC     8
#define BATCH    128
#define LEN      512
#define OUTL     505
#define NPATCH   (BATCH * OUTL)      // 64640
#define BM       64
#define NBLK_P   (NPATCH / BM)       // 1010
#define BLK_PER_CH 1010

typedef __attribute__((ext_vector_type(8))) short bf16x8;
typedef __attribute__((ext_vector_type(4))) float f32x4;

__device__ __forceinline__ ushort to_bf16(float f) {
    union { float f; unsigned int u; } v; v.f = f;
    unsigned int b = v.u + 0x7FFFu + ((v.u >> 16) & 1u);
    return (ushort)(b >> 16);
}

__device__ __forceinline__ void load_lds16(const void* g, void* l) {
    __builtin_amdgcn_global_load_lds(
        (const __attribute__((address_space(1))) unsigned int*)g,
        (__attribute__((address_space(3))) unsigned int*)l, 16, 0, 0);
}

// quad_perm lane swaps: xor1 -> 0xB1, xor2 -> 0x4E
template <int CTRL>
__device__ __forceinline__ float dpp_xor(float x) {
    int i = __float_as_int(x);
    int r = __builtin_amdgcn_update_dpp(0, i, CTRL, 0xF, 0xF, true);
    return __int_as_float(r);
}

// Shared 4-layer circuit body on the 4-lane x 64-reg state layout.
// lane bits: b0 = wire0, b7 = wire7; reg bits: wire q (1..6) -> bit (6-q).
__device__ __forceinline__ void run_layers(float st[64], const float* wk, int b0, int b7) {
#pragma unroll 1
    for (int layer = 0; layer < NLAYERS; ++layer) {
        float wc[NQ], wsn[NQ];
#pragma unroll
        for (int q = 0; q < NQ; ++q) {
            float half = 0.5f * wk[layer * NQ + q];
            wc[q]  = __cosf(half);
            wsn[q] = __sinf(half);
        }
        { // RY wire0 (lane bit1)
            const float sg = b0 ? wsn[0] : -wsn[0];
#pragma unroll
            for (int r = 0; r < 64; ++r) {
                float p = dpp_xor<0x4E>(st[r]);
                st[r] = fmaf(wc[0], st[r], sg * p);
            }
        }
#pragma unroll
        for (int q = 1; q <= 6; ++q) { // RY wires 1..6 in-register
            const int m = 1 << (6 - q);
#pragma unroll
            for (int r = 0; r < 64; ++r) {
                if (r & m) continue;
                float a0 = st[r], a1 = st[r + m];
                st[r]     = fmaf(wc[q], a0, -wsn[q] * a1);
                st[r + m] = fmaf(wc[q], a1,  wsn[q] * a0);
            }
        }
        { // RY wire7 (lane bit0)
            const float sg = b7 ? wsn[7] : -wsn[7];
#pragma unroll
            for (int r = 0; r < 64; ++r) {
                float p = dpp_xor<0xB1>(st[r]);
                st[r] = fmaf(wc[7], st[r], sg * p);
            }
        }
        // CNOT(0,1)
#pragma unroll
        for (int r = 0; r < 32; ++r) {
            float t0 = st[r], t1 = st[r + 32];
            st[r]      = b0 ? t1 : t0;
            st[r + 32] = b0 ? t0 : t1;
        }
        // CNOT(q,q+1) q=1..5: compile-time reg permutation
#pragma unroll
        for (int q = 1; q <= 5; ++q) {
            const int cm = 1 << (6 - q);
            const int tm = 1 << (5 - q);
#pragma unroll
            for (int r = 0; r < 64; ++r) {
                if ((r & cm) && !(r & tm)) {
                    float t = st[r]; st[r] = st[r + tm]; st[r + tm] = t;
                }
            }
        }
        // CNOT(6,7)
#pragma unroll
        for (int r = 1; r < 64; r += 2) st[r] = dpp_xor<0xB1>(st[r]);
    }
}

// ---------------- Kernel 1: build W2[k][slab j>>5][i][swz(j&31, i)] = M_k[i][j] (bf16)
__global__ __launch_bounds__(256) void build_m(const float* __restrict__ w,
                                               ushort* __restrict__ W2) {
    const int tid  = threadIdx.x;
    const int lane = tid & 63;
    const int k    = blockIdx.x >> 2;
    const int j    = ((blockIdx.x & 3) << 6) | (tid >> 2);
    const int b0 = (lane >> 1) & 1;
    const int b7 = lane & 1;

    float st[64];
    const int r0 = (j >> 1) & 63;
    const bool mine = (b0 == ((j >> 7) & 1)) && (b7 == (j & 1));
#pragma unroll
    for (int r = 0; r < 64; ++r) st[r] = (mine && r == r0) ? 1.0f : 0.0f;

    run_layers(st, w + k * (NLAYERS * NQ), b0, b7);

    const int kk = j & 31, slab = j >> 5;
#pragma unroll
    for (int r = 0; r < 64; ++r) {
        int i  = (b0 << 7) | (r << 1) | b7;
        int ks = (kk & 7) | ((((kk >> 3) ^ (i & 3)) & 3) << 3);
        size_t idx = (((size_t)(k * 8 + slab)) * 256 + i) * 32 + ks;
        W2[idx] = to_bf16(st[r]);
    }
}

// ---------------- Kernel 2: fused embed + GEMM(MFMA) + signed-square reduce
__global__ __launch_bounds__(256) void qconv_mfma(const float* __restrict__ x,
                                                  const ushort* __restrict__ W2,
                                                  float* __restrict__ out) {
    __shared__ ushort Alds[64 * 256];   // [row][swizzled j] bf16, 32 KB
    __shared__ ushort Blds[2][8192];    // double-buffered B k-slab, 2 x 16 KB
    __shared__ float  red[4][64];

    const int tid  = threadIdx.x;
    const int lane = tid & 63;
    const int wv   = tid >> 6;
    const int k     = blockIdx.x / NBLK_P;
    const int pblk  = blockIdx.x % NBLK_P;
    const int pbase = pblk * BM;
    const ushort* Wk = W2 + (size_t)k * 65536;

    // issue stage of slab 0 early (hides L2 latency under embed)
#pragma unroll
    for (int n = 0; n < 4; ++n)
        load_lds16(Wk + n * 2048 + tid * 8, &Blds[0][n * 2048 + tid * 8]);

    // ---- embed: one patch per quad
    {
        const int quad = tid >> 2;
        const int b0 = (lane >> 1) & 1, b7 = lane & 1;
        const int p = pbase + quad;
        const int b = p / OUTL, ol = p - b * OUTL;
        const float* xp = x + b * LEN + ol;
        float ec[NQ], es[NQ];
#pragma unroll
        for (int q = 0; q < NQ; ++q) {
            float half = xp[q] * 1.5707963267948966f;
            ec[q] = __cosf(half);
            es[q] = __sinf(half);
        }
        float st[64];
        st[0] = (b0 ? es[0] : ec[0]) * (b7 ? es[7] : ec[7]);
#pragma unroll
        for (int q = 1; q <= 6; ++q) {
            const int m = 1 << (6 - q);
#pragma unroll
            for (int jj = (1 << (q - 1)) - 1; jj >= 0; --jj) {
                float v = st[jj * 2 * m];
                st[jj * 2 * m + m] = v * es[q];
                st[jj * 2 * m]     = v * ec[q];
            }
        }
        const int row = quad;
#pragma unroll
        for (int r = 0; r < 64; ++r) {
            int j = (b0 << 7) | (r << 1) | b7;
            int kg = ((j >> 3) ^ (row & 7)) & 31;
            Alds[row * 256 + kg * 8 + (j & 7)] = to_bf16(st[r]);
        }
    }

    f32x4 acc[4][4];
#pragma unroll
    for (int a = 0; a < 4; ++a)
#pragma unroll
        for (int bq = 0; bq < 4; ++bq) acc[a][bq] = (f32x4){0.f, 0.f, 0.f, 0.f};

    const int rowoff = lane & 15;
    const int g = lane >> 4;

    for (int s = 0; s < 8; ++s) {
        asm volatile("s_waitcnt vmcnt(0)" ::: "memory");
        __syncthreads();
        if (s < 7) {
#pragma unroll
            for (int n = 0; n < 4; ++n)
                load_lds16(Wk + (s + 1) * 8192 + n * 2048 + tid * 8,
                           &Blds[(s + 1) & 1][n * 2048 + tid * 8]);
        }
        const ushort* Bp = Blds[s & 1];
        bf16x8 af[4], bfr[4];
#pragma unroll
        for (int rt = 0; rt < 4; ++rt) {
            int row = rt * 16 + rowoff;
            int kg = ((s * 4 + g) ^ (row & 7)) & 31;
            af[rt] = *(const bf16x8*)&Alds[row * 256 + kg * 8];
        }
#pragma unroll
        for (int ct = 0; ct < 4; ++ct) {
            int col = (wv << 6) + ct * 16 + rowoff;
            int gg = (g ^ (col & 3)) & 3;
            bfr[ct] = *(const bf16x8*)&Bp[col * 32 + gg * 8];
        }
#pragma unroll
        for (int rt = 0; rt < 4; ++rt)
#pragma unroll
            for (int ct = 0; ct < 4; ++ct)
                acc[rt][ct] = __builtin_amdgcn_mfma_f32_16x16x32_bf16(
                    af[rt], bfr[ct], acc[rt][ct], 0, 0, 0);
    }

    // ---- epilogue: out[p] = sum_i sign(i) * C[p][i]^2
    float sg[4];
#pragma unroll
    for (int ct = 0; ct < 4; ++ct) {
        int col = (wv << 6) + ct * 16 + rowoff;
        sg[ct] = (__builtin_popcount(col) & 1) ? -1.0f : 1.0f;
    }
#pragma unroll
    for (int rt = 0; rt < 4; ++rt) {
        f32x4 part = (f32x4){0.f, 0.f, 0.f, 0.f};
#pragma unroll
        for (int ct = 0; ct < 4; ++ct) part += (acc[rt][ct] * acc[rt][ct]) * sg[ct];
#pragma unroll
        for (int reg = 0; reg < 4; ++reg) {
            float v = part[reg];
            v += __shfl_xor(v, 1, 64);
            v += __shfl_xor(v, 2, 64);
            v += __shfl_xor(v, 4, 64);
            v += __shfl_xor(v, 8, 64);
            if ((lane & 15) == 0) red[wv][rt * 16 + (lane >> 4) * 4 + reg] = v;
        }
    }
    __syncthreads();
    if (tid < 64) {
        float o = red[0][tid] + red[1][tid] + red[2][tid] + red[3][tid];
        int p = pbase + tid;
        int b = p / OUTL, ol = p - b * OUTL;
        out[b * (OUTC * OUTL) + k * OUTL + ol] = o;
    }
}

// ---------------- Fallback: verified direct simulator (213 us)
__global__ __launch_bounds__(256) void qconv_direct(const float* __restrict__ x,
                                                    const float* __restrict__ w,
                                                    float* __restrict__ out) {
    const int lane = threadIdx.x & 63;
    const int wave = threadIdx.x >> 6;
    const int bi   = blockIdx.x;
    const int k    = bi / BLK_PER_CH;
    const int pblk = bi % BLK_PER_CH;
    const int patch = pblk * 64 + wave * 16 + (lane >> 2);
    const int b0 = (lane >> 1) & 1;
    const int b7 = lane & 1;
    const int b  = patch / OUTL;
    const int ol = patch - b * OUTL;
    const float* xp = x + b * LEN + ol;

    float ec[NQ], es[NQ];
#pragma unroll
    for (int q = 0; q < NQ; ++q) {
        float half = xp[q] * 1.5707963267948966f;
        ec[q] = __cosf(half);
        es[q] = __sinf(half);
    }
    float st[64];
    st[0] = (b0 ? es[0] : ec[0]) * (b7 ? es[7] : ec[7]);
#pragma unroll
    for (int q = 1; q <= 6; ++q) {
        const int m = 1 << (6 - q);
#pragma unroll
        for (int j = (1 << (q - 1)) - 1; j >= 0; --j) {
            float v = st[j * 2 * m];
            st[j * 2 * m + m] = v * es[q];
            st[j * 2 * m]     = v * ec[q];
        }
    }
    run_layers(st, w + k * (NLAYERS * NQ), b0, b7);

    float accp = 0.0f, accm = 0.0f;
#pragma unroll
    for (int r = 0; r < 64; ++r) {
        if (__builtin_popcount(r) & 1) accm = fmaf(st[r], st[r], accm);
        else                           accp = fmaf(st[r], st[r], accp);
    }
    float v = accp - accm;
    if (b0 ^ b7) v = -v;
    v += dpp_xor<0xB1>(v);
    v += dpp_xor<0x4E>(v);
    if ((lane & 3) == 0) out[b * (OUTC * OUTL) + k * OUTL + ol] = v;
}

extern "C" void kernel_launch(void* const* d_in, const int* in_sizes, int n_in,
                              void* d_out, int out_size, void* d_ws, size_t ws_size,
                              hipStream_t stream) {
    const float* x = (const float*)d_in[0];   // (128,1,512) f32
    const float* w = (const float*)d_in[1];   // (8,32) f32
    float* out = (float*)d_out;               // (128,8,505) f32

    if (ws_size < (size_t)(8 * 256 * 256 * 2)) {
        qconv_direct<<<dim3(OUTC * BLK_PER_CH), 256, 0, stream>>>(x, w, out);
        return;
    }
    ushort* W2 = (ushort*)d_ws;               // 1 MB: 8 ch x 8 slabs x 256 i x 32 kk (bf16)
    build_m<<<dim3(32), 256, 0, stream>>>(w, W2);
    qconv_mfma<<<dim3(NBLK_P * OUTC), 256, 0, stream>>>(x, W2, out);
}

// Round 8
// 105.129 us; speedup vs baseline: 2.0240x; 1.3932x over previous
//
#include <hip/hip_runtime.h>
#include <math.h>

#define NQ       8
#define NLAYERS  4
#define OUTC     8
#define BATCH    128
#define LEN      512
#define OUTL     505
#define NPATCH   (BATCH * OUTL)      // 64640
#define BM       64
#define NBLK     (NPATCH / BM)       // 1010
#define BLK_PER_CH 1010

typedef __attribute__((ext_vector_type(8))) short bf16x8;
typedef __attribute__((ext_vector_type(4))) float f32x4;

__device__ __forceinline__ ushort to_bf16(float f) {
    union { float f; unsigned int u; } v; v.f = f;
    unsigned int b = v.u + 0x7FFFu + ((v.u >> 16) & 1u);
    return (ushort)(b >> 16);
}

// packed f32x2 -> bf16x2 (RTNE), single instruction
__device__ __forceinline__ unsigned pk_bf16(float lo, float hi) {
    unsigned r;
    asm("v_cvt_pk_bf16_f32 %0, %1, %2" : "=v"(r) : "v"(lo), "v"(hi));
    return r;
}

__device__ __forceinline__ void load_lds16(const void* g, void* l) {
    __builtin_amdgcn_global_load_lds(
        (const __attribute__((address_space(1))) unsigned int*)g,
        (__attribute__((address_space(3))) unsigned int*)l, 16, 0, 0);
}

// stage one 4KB B-slab segment (wave-private): 4 x global_load_lds_dwordx4
__device__ __forceinline__ void stage_b(const ushort* __restrict__ W2, int seg,
                                        ushort* dst, int lane) {
    const ushort* src = W2 + (size_t)seg * 2048 + lane * 8;
#pragma unroll
    for (int n = 0; n < 4; ++n)
        load_lds16(src + n * 512, dst + n * 512);
}

// quad_perm lane swaps: xor1 -> 0xB1, xor2 -> 0x4E
template <int CTRL>
__device__ __forceinline__ float dpp_xor(float x) {
    int i = __float_as_int(x);
    int r = __builtin_amdgcn_update_dpp(0, i, CTRL, 0xF, 0xF, true);
    return __int_as_float(r);
}

// 4-layer circuit on the 4-lane x 64-reg state layout (verified R5).
__device__ __forceinline__ void run_layers(float st[64], const float* wk, int b0, int b7) {
#pragma unroll 1
    for (int layer = 0; layer < NLAYERS; ++layer) {
        float wc[NQ], wsn[NQ];
#pragma unroll
        for (int q = 0; q < NQ; ++q) {
            float half = 0.5f * wk[layer * NQ + q];
            wc[q]  = __cosf(half);
            wsn[q] = __sinf(half);
        }
        {
            const float sg = b0 ? wsn[0] : -wsn[0];
#pragma unroll
            for (int r = 0; r < 64; ++r) {
                float p = dpp_xor<0x4E>(st[r]);
                st[r] = fmaf(wc[0], st[r], sg * p);
            }
        }
#pragma unroll
        for (int q = 1; q <= 6; ++q) {
            const int m = 1 << (6 - q);
#pragma unroll
            for (int r = 0; r < 64; ++r) {
                if (r & m) continue;
                float a0 = st[r], a1 = st[r + m];
                st[r]     = fmaf(wc[q], a0, -wsn[q] * a1);
                st[r + m] = fmaf(wc[q], a1,  wsn[q] * a0);
            }
        }
        {
            const float sg = b7 ? wsn[7] : -wsn[7];
#pragma unroll
            for (int r = 0; r < 64; ++r) {
                float p = dpp_xor<0xB1>(st[r]);
                st[r] = fmaf(wc[7], st[r], sg * p);
            }
        }
#pragma unroll
        for (int r = 0; r < 32; ++r) {
            float t0 = st[r], t1 = st[r + 32];
            st[r]      = b0 ? t1 : t0;
            st[r + 32] = b0 ? t0 : t1;
        }
#pragma unroll
        for (int q = 1; q <= 5; ++q) {
            const int cm = 1 << (6 - q);
            const int tm = 1 << (5 - q);
#pragma unroll
            for (int r = 0; r < 64; ++r) {
                if ((r & cm) && !(r & tm)) {
                    float t = st[r]; st[r] = st[r + tm]; st[r + tm] = t;
                }
            }
        }
#pragma unroll
        for (int r = 1; r < 64; r += 2) st[r] = dpp_xor<0xB1>(st[r]);
    }
}

// ---------------- Kernel 1: build W2 (bf16 circuit matrices, pre-swizzled B layout)
// W2 element (ch k, col i, slab, kk): seg = (k*8+slab)*4 + (i>>6)
// off = seg*2048 + (i&63)*32 + phys(kk>>3, i)*8 + (kk&7); phys = ((kk>>3)+((i>>2)&15))&3
__global__ __launch_bounds__(256) void build_m(const float* __restrict__ w,
                                               ushort* __restrict__ W2) {
    const int tid  = threadIdx.x;
    const int lane = tid & 63;
    const int k    = blockIdx.x >> 2;
    const int j    = ((blockIdx.x & 3) << 6) | (tid >> 2);   // basis column = K index
    const int b0 = (lane >> 1) & 1;
    const int b7 = lane & 1;

    float st[64];
    const int r0 = (j >> 1) & 63;
    const bool mine = (b0 == ((j >> 7) & 1)) && (b7 == (j & 1));
#pragma unroll
    for (int r = 0; r < 64; ++r) st[r] = (mine && r == r0) ? 1.0f : 0.0f;

    run_layers(st, w + k * (NLAYERS * NQ), b0, b7);

    const int kk = j & 31, slab = j >> 5;
#pragma unroll
    for (int r = 0; r < 64; ++r) {
        int i  = (b0 << 7) | (r << 1) | b7;
        int cl = i & 63;
        int seg = (k * 8 + slab) * 4 + (i >> 6);
        int phys = ((kk >> 3) + (cl >> 2)) & 3;
        W2[(size_t)seg * 2048 + cl * 32 + phys * 8 + (kk & 7)] = to_bf16(st[r]);
    }
}

// ---------------- Kernel 2: 64 patches x 8 channels per block, barrier-free K-loop
__global__ __launch_bounds__(256, 2) void qconv_mfma(const float* __restrict__ x,
                                                     const ushort* __restrict__ W2,
                                                     float* __restrict__ out) {
    __shared__ ushort Alds[64 * 256];      // 32 KB, A tile (swizzled 16B chunks)
    __shared__ ushort Bw[4][2][2048];      // 32 KB, per-wave double-buffered B slab
    __shared__ float  red[OUTC * 4 * 64];  // 8 KB, per-channel per-wave partials

    const int tid  = threadIdx.x;
    const int lane = tid & 63;
    const int wv   = tid >> 6;
    const int u    = lane & 15;
    const int g    = lane >> 4;
    const int pbase = blockIdx.x * BM;

    // prologue: stage slabs m=0,1 (hidden under embed)
    stage_b(W2, 0 * 4 + wv, &Bw[wv][0][0], lane);
    stage_b(W2, 1 * 4 + wv, &Bw[wv][1][0], lane);

    // ---- embed: lane embeds patch pbase+lane, j-block jb = wave index
    {
        const int row = lane;
        const int jb  = wv;
        const int p = pbase + row;
        const int b = p / OUTL, ol = p - b * OUTL;
        const float* xp = x + b * LEN + ol;
        float ec[NQ], es[NQ];
#pragma unroll
        for (int q = 0; q < NQ; ++q) {
            float half = xp[q] * 1.5707963267948966f;
            ec[q] = __cosf(half);
            es[q] = __sinf(half);
        }
        float st[64];
        st[0] = (jb & 2 ? es[0] : ec[0]) * (jb & 1 ? es[1] : ec[1]);
#pragma unroll
        for (int q = 2; q <= 7; ++q) {           // wires 2..7 -> r bits 5..0
            const int m = 1 << (7 - q);
#pragma unroll
            for (int jj = (1 << (q - 2)) - 1; jj >= 0; --jj) {
                float v = st[jj * 2 * m];
                st[jj * 2 * m + m] = v * es[q];
                st[jj * 2 * m]     = v * ec[q];
            }
        }
#pragma unroll
        for (int cc = 0; cc < 8; ++cc) {
            uint4 vv;
            vv.x = pk_bf16(st[cc * 8 + 0], st[cc * 8 + 1]);
            vv.y = pk_bf16(st[cc * 8 + 2], st[cc * 8 + 3]);
            vv.z = pk_bf16(st[cc * 8 + 4], st[cc * 8 + 5]);
            vv.w = pk_bf16(st[cc * 8 + 6], st[cc * 8 + 7]);
            int phys = ((jb * 8 + cc) ^ (row & 7)) & 31;
            *(uint4*)((char*)Alds + row * 512 + phys * 16) = vv;
        }
    }
    __syncthreads();

    // ---- hoist all A fragments to registers (static indices -> stays in VGPRs)
    bf16x8 af[8][4];
#pragma unroll
    for (int s = 0; s < 8; ++s)
#pragma unroll
        for (int rt = 0; rt < 4; ++rt) {
            int row = rt * 16 + u;
            int phys = ((s * 4 + g) ^ (row & 7)) & 31;
            af[s][rt] = *(const bf16x8*)((const char*)Alds + row * 512 + phys * 16);
        }

    const int pu = __builtin_popcount(u) & 1;
    const int pw = __builtin_popcount(wv) & 1;
    const int bphys = (g + (u >> 2)) & 3;       // B chunk for this lane (ct-invariant)

#pragma unroll 1
    for (int ch = 0; ch < 8; ++ch) {
        f32x4 acc[4][4];
#pragma unroll
        for (int a = 0; a < 4; ++a)
#pragma unroll
            for (int c = 0; c < 4; ++c) acc[a][c] = (f32x4){0.f, 0.f, 0.f, 0.f};

#pragma unroll
        for (int s = 0; s < 8; ++s) {
            if (s == 7 && ch == 7) { asm volatile("s_waitcnt vmcnt(0)" ::: "memory"); }
            else                   { asm volatile("s_waitcnt vmcnt(4)" ::: "memory"); }
            const ushort* Bp = &Bw[wv][s & 1][0];
            bf16x8 bfr[4];
#pragma unroll
            for (int ct = 0; ct < 4; ++ct)
                bfr[ct] = *(const bf16x8*)(Bp + (ct * 16 + u) * 32 + bphys * 8);
            asm volatile("s_waitcnt lgkmcnt(0)" ::: "memory");
            if (s < 6 || ch < 7)
                stage_b(W2, (ch * 8 + s + 2) * 4 + wv, &Bw[wv][s & 1][0], lane);
#pragma unroll
            for (int rt = 0; rt < 4; ++rt)
#pragma unroll
                for (int ct = 0; ct < 4; ++ct)
                    acc[rt][ct] = __builtin_amdgcn_mfma_f32_16x16x32_bf16(
                        af[s][rt], bfr[ct], acc[rt][ct], 0, 0, 0);
        }

        // per-channel epilogue: signed-square, reduce over this wave's 64 cols
#pragma unroll
        for (int rt = 0; rt < 4; ++rt) {
            f32x4 part = (f32x4){0.f, 0.f, 0.f, 0.f};
#pragma unroll
            for (int ct = 0; ct < 4; ++ct) {
                float sgn = ((pu + pw + __builtin_popcount(ct)) & 1) ? -1.0f : 1.0f;
                part += (acc[rt][ct] * acc[rt][ct]) * sgn;
            }
#pragma unroll
            for (int reg = 0; reg < 4; ++reg) {
                float v = part[reg];
                v += __shfl_xor(v, 1, 64);
                v += __shfl_xor(v, 2, 64);
                v += __shfl_xor(v, 4, 64);
                v += __shfl_xor(v, 8, 64);
                if (u == 0) red[(ch * 4 + wv) * 64 + rt * 16 + g * 4 + reg] = v;
            }
        }
    }

    __syncthreads();
    // final: sum 4 wave-partials, store. 2 outputs/thread (8ch x 64 rows = 512)
#pragma unroll
    for (int e = 0; e < 2; ++e) {
        int idx = tid + e * 256;
        int ch = idx >> 6, row = idx & 63;
        float o = red[(ch * 4 + 0) * 64 + row] + red[(ch * 4 + 1) * 64 + row] +
                  red[(ch * 4 + 2) * 64 + row] + red[(ch * 4 + 3) * 64 + row];
        int p = pbase + row;
        int b = p / OUTL, ol = p - b * OUTL;
        out[b * (OUTC * OUTL) + ch * OUTL + ol] = o;
    }
}

// ---------------- Fallback: verified direct simulator (213 us)
__global__ __launch_bounds__(256) void qconv_direct(const float* __restrict__ x,
                                                    const float* __restrict__ w,
                                                    float* __restrict__ out) {
    const int lane = threadIdx.x & 63;
    const int wave = threadIdx.x >> 6;
    const int bi   = blockIdx.x;
    const int k    = bi / BLK_PER_CH;
    const int pblk = bi % BLK_PER_CH;
    const int patch = pblk * 64 + wave * 16 + (lane >> 2);
    const int b0 = (lane >> 1) & 1;
    const int b7 = lane & 1;
    const int b  = patch / OUTL;
    const int ol = patch - b * OUTL;
    const float* xp = x + b * LEN + ol;

    float ec[NQ], es[NQ];
#pragma unroll
    for (int q = 0; q < NQ; ++q) {
        float half = xp[q] * 1.5707963267948966f;
        ec[q] = __cosf(half);
        es[q] = __sinf(half);
    }
    float st[64];
    st[0] = (b0 ? es[0] : ec[0]) * (b7 ? es[7] : ec[7]);
#pragma unroll
    for (int q = 1; q <= 6; ++q) {
        const int m = 1 << (6 - q);
#pragma unroll
        for (int j = (1 << (q - 1)) - 1; j >= 0; --j) {
            float v = st[j * 2 * m];
            st[j * 2 * m + m] = v * es[q];
            st[j * 2 * m]     = v * ec[q];
        }
    }
    run_layers(st, w + k * (NLAYERS * NQ), b0, b7);

    float accp = 0.0f, accm = 0.0f;
#pragma unroll
    for (int r = 0; r < 64; ++r) {
        if (__builtin_popcount(r) & 1) accm = fmaf(st[r], st[r], accm);
        else                           accp = fmaf(st[r], st[r], accp);
    }
    float v = accp - accm;
    if (b0 ^ b7) v = -v;
    v += dpp_xor<0xB1>(v);
    v += dpp_xor<0x4E>(v);
    if ((lane & 3) == 0) out[b * (OUTC * OUTL) + k * OUTL + ol] = v;
}

extern "C" void kernel_launch(void* const* d_in, const int* in_sizes, int n_in,
                              void* d_out, int out_size, void* d_ws, size_t ws_size,
                              hipStream_t stream) {
    const float* x = (const float*)d_in[0];   // (128,1,512) f32
    const float* w = (const float*)d_in[1];   // (8,32) f32
    float* out = (float*)d_out;               // (128,8,505) f32

    if (ws_size < (size_t)(8 * 256 * 256 * 2)) {
        qconv_direct<<<dim3(OUTC * BLK_PER_CH), 256, 0, stream>>>(x, w, out);
        return;
    }
    ushort* W2 = (ushort*)d_ws;               // 1 MB bf16, pre-swizzled B layout
    build_m<<<dim3(32), 256, 0, stream>>>(w, W2);
    qconv_mfma<<<dim3(NBLK), 256, 0, stream>>>(x, W2, out);
}